// Round 1
// baseline (2531.718 us; speedup 1.0000x reference)
//
#include <hip/hip_runtime.h>
#include <math.h>

// CriticNetwork fused kernel, fp32 round-1 (correctness + baseline).
//
// Algebraic simplifications vs reference (validated by hand):
//  * inner MHA has seq_len==1 -> softmax==1 -> scores==comV; Wcq/Wck dead.
//  * concat @ W_out  ==  sum_h raw_h @ (Wcv @ W_out_h)  -> precomputed W_eff (768x128).
//  * score[b,k] = sur[b,k] . (Wk Wq^T) . own[b]        -> precomputed Mt, u = M@own.
//  * v_att = (sum_k alpha_k sur_k) @ Wv                -> one matvec, not K of them.

#define KN     8
#define OBS0V  80
#define OBS1V  160
#define OBS2V  384
#define DD     256
#define RPB    4     // batch rows per block

// Mt[l][i] = sum_j Wk[i][j] * Wq[l][j]   (transposed so u-loop reads coalesced)
__global__ void precompute_M(const float* __restrict__ Wk,
                             const float* __restrict__ Wq,
                             float* __restrict__ Mt) {
    __shared__ float wq[DD];
    const int l = blockIdx.x;   // 0..255
    const int i = threadIdx.x;  // 0..255
    wq[i] = Wq[l * DD + i];
    __syncthreads();
    const float4* wk4 = (const float4*)(Wk + (size_t)i * DD);
    float acc = 0.f;
#pragma unroll 8
    for (int j = 0; j < DD / 4; ++j) {
        const float4 a = wk4[j];
        const float4 b = *(const float4*)&wq[j * 4];
        acc += a.x * b.x + a.y * b.y + a.z * b.z + a.w * b.w;
    }
    Mt[l * DD + i] = acc;
}

// Weff[(h*256+i)][o] = sum_j Wcv[i][j] * W_out[(h*256+j)][o]
__global__ void precompute_Weff(const float* __restrict__ Wcv,
                                const float* __restrict__ Wout,
                                float* __restrict__ Weff) {
    const int bh = blockIdx.x;          // 0..767  = h*256 + i
    const int h = bh >> 8, i = bh & 255;
    const int o = threadIdx.x;          // 0..127
    const float* wrow = Wcv + (size_t)i * DD;   // block-uniform row
    float acc = 0.f;
#pragma unroll 4
    for (int j = 0; j < DD; ++j)
        acc += wrow[j] * Wout[(size_t)(h * DD + j) * 128 + o];
    Weff[(size_t)bh * 128 + o] = acc;
}

__launch_bounds__(256, 2)
__global__ void critic_main(const float* __restrict__ state0,
                            const float* __restrict__ state1,
                            const float* __restrict__ state2,
                            const float* __restrict__ W_own, const float* __restrict__ b_own,
                            const float* __restrict__ W_env, const float* __restrict__ b_env,
                            const float* __restrict__ W_sur, const float* __restrict__ b_sur,
                            const float* __restrict__ Wv,
                            const float* __restrict__ Mt, const float* __restrict__ Weff,
                            const float* __restrict__ b_out,
                            const float* __restrict__ W_j1, const float* __restrict__ b_j1,
                            const float* __restrict__ W_j2, const float* __restrict__ b_j2,
                            float* __restrict__ out) {
    __shared__ __align__(16) float cc_l[RPB][768];       // own | env | v_att
    __shared__ __align__(16) float sat_l[RPB][DD];       // s_att = sum_k alpha_k * sur_k
    __shared__ float masksum_l[RPB][KN];
    __shared__ float part8_l[4][8][RPB * KN];            // score partials
    __shared__ float alpha_l[RPB][KN];
    __shared__ __align__(16) float mpart_l[RPB][2][128];
    __shared__ __align__(16) float msum_l[RPB][128];

    const int t = threadIdx.x;
    const int bbase = blockIdx.x * RPB;
    const float* s2base = state2 + (size_t)bbase * (KN * OBS2V);

    // ---- masks: per (r,k) row sum of state2 (mean!=0 <=> sum!=0) ----
    {
        const int g = t >> 3, lane8 = t & 7;   // 32 groups of 8 lanes
        const int r = g >> 3, k = g & 7;
        const float* p = s2base + (size_t)r * (KN * OBS2V) + k * OBS2V;
        float s = 0.f;
#pragma unroll 4
        for (int i = lane8; i < OBS2V; i += 8) s += p[i];
        s += __shfl_down(s, 4, 8);
        s += __shfl_down(s, 2, 8);
        s += __shfl_down(s, 1, 8);
        if (lane8 == 0) masksum_l[r][k] = s;
    }

    // ---- own = relu(state0 @ W_own + b_own) -> cc[0:256] ----
    {
        float acc[RPB];
        const float bo = b_own[t];
#pragma unroll
        for (int r = 0; r < RPB; ++r) acc[r] = bo;
        const float* s0p = state0 + (size_t)bbase * OBS0V;
        for (int i = 0; i < OBS0V; i += 4) {
            const float w0 = W_own[(i + 0) * DD + t];
            const float w1 = W_own[(i + 1) * DD + t];
            const float w2 = W_own[(i + 2) * DD + t];
            const float w3 = W_own[(i + 3) * DD + t];
#pragma unroll
            for (int r = 0; r < RPB; ++r) {
                const float4 sv = *(const float4*)(s0p + r * OBS0V + i);  // block-uniform
                acc[r] += sv.x * w0 + sv.y * w1 + sv.z * w2 + sv.w * w3;
            }
        }
#pragma unroll
        for (int r = 0; r < RPB; ++r) cc_l[r][t] = fmaxf(acc[r], 0.f);
    }

    // ---- env = relu(state1 @ W_env + b_env) -> cc[256:512] ----
    {
        float acc[RPB];
        const float be = b_env[t];
#pragma unroll
        for (int r = 0; r < RPB; ++r) acc[r] = be;
        const float* s1p = state1 + (size_t)bbase * OBS1V;
        for (int i = 0; i < OBS1V; i += 4) {
            const float w0 = W_env[(i + 0) * DD + t];
            const float w1 = W_env[(i + 1) * DD + t];
            const float w2 = W_env[(i + 2) * DD + t];
            const float w3 = W_env[(i + 3) * DD + t];
#pragma unroll
            for (int r = 0; r < RPB; ++r) {
                const float4 sv = *(const float4*)(s1p + r * OBS1V + i);
                acc[r] += sv.x * w0 + sv.y * w1 + sv.z * w2 + sv.w * w3;
            }
        }
#pragma unroll
        for (int r = 0; r < RPB; ++r) cc_l[r][DD + t] = fmaxf(acc[r], 0.f);
    }
    __syncthreads();   // cc(own) + masksum visible

    // ---- u[i=t] = sum_l Mt[l][i] * own[l] ----
    float u[RPB] = {0.f, 0.f, 0.f, 0.f};
    for (int l = 0; l < DD; l += 4) {
        const float m0 = Mt[(l + 0) * DD + t];
        const float m1 = Mt[(l + 1) * DD + t];
        const float m2 = Mt[(l + 2) * DD + t];
        const float m3 = Mt[(l + 3) * DD + t];
#pragma unroll
        for (int r = 0; r < RPB; ++r) {
            const float4 ov = *(const float4*)&cc_l[r][l];
            u[r] += ov.x * m0 + ov.y * m1 + ov.z * m2 + ov.w * m3;
        }
    }

    // ---- sur[r][k][j=t] = relu(state2 @ W_sur + b_sur) ----
    float sur[RPB][KN];
    {
        const float bs = b_sur[t];
#pragma unroll
        for (int r = 0; r < RPB; ++r)
#pragma unroll
            for (int k = 0; k < KN; ++k) sur[r][k] = bs;
        for (int i = 0; i < OBS2V; i += 4) {
            const float w0 = W_sur[(i + 0) * DD + t];
            const float w1 = W_sur[(i + 1) * DD + t];
            const float w2 = W_sur[(i + 2) * DD + t];
            const float w3 = W_sur[(i + 3) * DD + t];
#pragma unroll
            for (int r = 0; r < RPB; ++r) {
                const float* s2r = s2base + (size_t)r * (KN * OBS2V) + i;
#pragma unroll
                for (int k = 0; k < KN; ++k) {
                    const float4 sv = *(const float4*)(s2r + k * OBS2V);  // block-uniform
                    sur[r][k] += sv.x * w0 + sv.y * w1 + sv.z * w2 + sv.w * w3;
                }
            }
        }
#pragma unroll
        for (int r = 0; r < RPB; ++r)
#pragma unroll
            for (int k = 0; k < KN; ++k) sur[r][k] = fmaxf(sur[r][k], 0.f);
    }

    // ---- score[r][k] = sum_j sur[r][k][j] * u[r][j]  (block reduction) ----
    {
        const int wv = t >> 6, l8 = t & 63;
#pragma unroll
        for (int r = 0; r < RPB; ++r)
#pragma unroll
            for (int k = 0; k < KN; ++k) {
                float p = sur[r][k] * u[r];
                p += __shfl_down(p, 32);
                p += __shfl_down(p, 16);
                p += __shfl_down(p, 8);
                if (l8 < 8) part8_l[wv][l8][r * KN + k] = p;
            }
    }
    __syncthreads();

    // ---- softmax over K (threads 0..31, one per (r,k)) ----
    if (t < 32) {
        const int r = t >> 3, k = t & 7;
        float s = 0.f;
#pragma unroll
        for (int w4 = 0; w4 < 4; ++w4)
#pragma unroll
            for (int j = 0; j < 8; ++j) s += part8_l[w4][j][t];
        const bool msk = (masksum_l[r][k] != 0.f);
        const float sval = msk ? s * 0.0625f : -INFINITY;   // /sqrt(256)
        float mx = sval;
        mx = fmaxf(mx, __shfl_xor(mx, 4, 8));
        mx = fmaxf(mx, __shfl_xor(mx, 2, 8));
        mx = fmaxf(mx, __shfl_xor(mx, 1, 8));
        const float e = msk ? expf(sval - mx) : 0.f;
        float dn = e;
        dn += __shfl_xor(dn, 4, 8);
        dn += __shfl_xor(dn, 2, 8);
        dn += __shfl_xor(dn, 1, 8);
        alpha_l[r][k] = (dn > 0.f) ? e / dn : 0.f;
    }
    __syncthreads();

    // ---- s_att = sum_k alpha_k * sur_k ----
#pragma unroll
    for (int r = 0; r < RPB; ++r) {
        float s = 0.f;
#pragma unroll
        for (int k = 0; k < KN; ++k) s += alpha_l[r][k] * sur[r][k];
        sat_l[r][t] = s;
    }
    __syncthreads();

    // ---- v_att[j=t] = sum_l s_att[l] * Wv[l][j] -> cc[512:768] ----
    {
        float va[RPB] = {0.f, 0.f, 0.f, 0.f};
        for (int l = 0; l < DD; l += 4) {
            const float w0 = Wv[(l + 0) * DD + t];
            const float w1 = Wv[(l + 1) * DD + t];
            const float w2 = Wv[(l + 2) * DD + t];
            const float w3 = Wv[(l + 3) * DD + t];
#pragma unroll
            for (int r = 0; r < RPB; ++r) {
                const float4 sv = *(const float4*)&sat_l[r][l];
                va[r] += sv.x * w0 + sv.y * w1 + sv.z * w2 + sv.w * w3;
            }
        }
#pragma unroll
        for (int r = 0; r < RPB; ++r) cc_l[r][512 + t] = va[r];
    }
    __syncthreads();

    // ---- multi_out[o] = cc @ W_eff + b_out  (split 768-dot across 2 halves) ----
    {
        const int o = t & 127, half = t >> 7;
        float mo[RPB];
        const float bo2 = (half == 0) ? b_out[o] : 0.f;
#pragma unroll
        for (int r = 0; r < RPB; ++r) mo[r] = bo2;
        const int ib = half * 384;
        for (int i = 0; i < 384; i += 4) {
            const float w0 = Weff[(size_t)(ib + i + 0) * 128 + o];
            const float w1 = Weff[(size_t)(ib + i + 1) * 128 + o];
            const float w2 = Weff[(size_t)(ib + i + 2) * 128 + o];
            const float w3 = Weff[(size_t)(ib + i + 3) * 128 + o];
#pragma unroll
            for (int r = 0; r < RPB; ++r) {
                const float4 cv = *(const float4*)&cc_l[r][ib + i];
                mo[r] += cv.x * w0 + cv.y * w1 + cv.z * w2 + cv.w * w3;
            }
        }
#pragma unroll
        for (int r = 0; r < RPB; ++r) mpart_l[r][half][o] = mo[r];
    }
    __syncthreads();
    if (t < 128) {
#pragma unroll
        for (int r = 0; r < RPB; ++r)
            msum_l[r][t] = mpart_l[r][0][t] + mpart_l[r][1][t];
    }
    __syncthreads();

    // ---- hidden = relu(multi_out @ W_j1 + b_j1); q = hidden @ W_j2 + b_j2 ----
    {
        const int rr = t >> 6, h = t & 63;   // wave rr handles batch row rr
        float acc = b_j1[h];
        for (int o2 = 0; o2 < 128; o2 += 4) {
            const float w0 = W_j1[(o2 + 0) * 64 + h];
            const float w1 = W_j1[(o2 + 1) * 64 + h];
            const float w2 = W_j1[(o2 + 2) * 64 + h];
            const float w3 = W_j1[(o2 + 3) * 64 + h];
            const float4 mv = *(const float4*)&msum_l[rr][o2];
            acc += mv.x * w0 + mv.y * w1 + mv.z * w2 + mv.w * w3;
        }
        acc = fmaxf(acc, 0.f);
        float p = acc * W_j2[h];
        p += __shfl_down(p, 32);
        p += __shfl_down(p, 16);
        p += __shfl_down(p, 8);
        p += __shfl_down(p, 4);
        p += __shfl_down(p, 2);
        p += __shfl_down(p, 1);
        if (h == 0) out[bbase + rr] = p + b_j2[0];
    }
}

extern "C" void kernel_launch(void* const* d_in, const int* in_sizes, int n_in,
                              void* d_out, int out_size, void* d_ws, size_t ws_size,
                              hipStream_t stream) {
    (void)n_in; (void)out_size; (void)ws_size;
    const float* state0 = (const float*)d_in[0];
    const float* state1 = (const float*)d_in[1];
    const float* state2 = (const float*)d_in[2];
    const float* W_own  = (const float*)d_in[3];
    const float* b_own  = (const float*)d_in[4];
    const float* W_env  = (const float*)d_in[5];
    const float* b_env  = (const float*)d_in[6];
    const float* W_sur  = (const float*)d_in[7];
    const float* b_sur  = (const float*)d_in[8];
    const float* Wq     = (const float*)d_in[9];
    const float* Wk     = (const float*)d_in[10];
    const float* Wv     = (const float*)d_in[11];
    // d_in[12] = Wcq, d_in[13] = Wck : dead code (seq_len==1 softmax == 1)
    const float* Wcv    = (const float*)d_in[14];
    const float* W_out  = (const float*)d_in[15];
    const float* b_out  = (const float*)d_in[16];
    const float* W_j1   = (const float*)d_in[17];
    const float* b_j1   = (const float*)d_in[18];
    const float* W_j2   = (const float*)d_in[19];
    const float* b_j2   = (const float*)d_in[20];
    float* out = (float*)d_out;

    float* Mt   = (float*)d_ws;          // 256*256 f32
    float* Weff = Mt + 256 * 256;        // 768*128 f32

    const int B = in_sizes[0] / OBS0V;   // 32768

    precompute_M<<<256, 256, 0, stream>>>(Wk, Wq, Mt);
    precompute_Weff<<<768, 128, 0, stream>>>(Wcv, W_out, Weff);
    critic_main<<<B / RPB, 256, 0, stream>>>(state0, state1, state2,
        W_own, b_own, W_env, b_env, W_sur, b_sur, Wv, Mt, Weff,
        b_out, W_j1, b_j1, W_j2, b_j2, out);
}

// Round 3
// 794.118 us; speedup vs baseline: 3.1881x; 3.1881x over previous
//
#include <hip/hip_runtime.h>
#include <hip/hip_bf16.h>
#include <math.h>

// CriticNetwork fused MFMA kernel (round 3 = round 2 + s_spart index fix).
// Algebra (validated round 1, absmax 4.9e-4 in fp32):
//  * inner MHA seq_len==1 -> softmax==1 -> Wcq/Wck dead.
//  * concat@W_out == cc @ Weff, Weff[(h*256+i)][o] = sum_j Wcv[i][j] W_out[h*256+j][o]
//  * score[b,k] = sur[b,k] . u[b],  u = own @ Mt2, Mt2[l][i] = sum_j Wk[i][j] Wq[l][j]
//  * v_att = (sum_k alpha_k sur_k) @ Wv
// Round 3 fix: score partials are per-column-half (wn), not per-wave (w) —
// round 2 read 2 uninitialized LDS slots per row in the softmax sum.

typedef unsigned int u32;
typedef __attribute__((ext_vector_type(8))) short bf16x8;
typedef __attribute__((ext_vector_type(4))) float f32x4;

#define KN     8
#define OBS0V  80
#define OBS1V  160
#define OBS2V  384
#define DD     256
#define MB     16   // batch rows per block

__device__ inline void gl2lds16(const void* g, void* l) {
    __builtin_amdgcn_global_load_lds(
        (const __attribute__((address_space(1))) u32*)g,
        (__attribute__((address_space(3))) u32*)l, 16, 0, 0);
}

__device__ inline ushort f2bf(float x) {
    union { __hip_bfloat16 h; ushort u; } c;
    c.h = __float2bfloat16(x);
    return c.u;
}
__device__ inline float bf2f(ushort u) {
    union { ushort s[2]; float f; } c;
    c.s[0] = 0; c.s[1] = u;
    return c.f;
}
__device__ inline void pack_store8(void* dst, float4 a, float4 b) {
    union { ushort u[8]; uint4 q; } pk;
    pk.u[0]=f2bf(a.x); pk.u[1]=f2bf(a.y); pk.u[2]=f2bf(a.z); pk.u[3]=f2bf(a.w);
    pk.u[4]=f2bf(b.x); pk.u[5]=f2bf(b.y); pk.u[6]=f2bf(b.z); pk.u[7]=f2bf(b.w);
    *(uint4*)dst = pk.q;
}

// ---------------- prep kernels (fp32, tiny) ----------------
__global__ void precompute_M(const float* __restrict__ Wk,
                             const float* __restrict__ Wq,
                             float* __restrict__ Mt) {
    __shared__ float wq[DD];
    const int l = blockIdx.x, i = threadIdx.x;
    wq[i] = Wq[l * DD + i];
    __syncthreads();
    const float4* wk4 = (const float4*)(Wk + (size_t)i * DD);
    float acc = 0.f;
#pragma unroll 8
    for (int j = 0; j < DD / 4; ++j) {
        const float4 a = wk4[j];
        const float4 b = *(const float4*)&wq[j * 4];
        acc += a.x * b.x + a.y * b.y + a.z * b.z + a.w * b.w;
    }
    Mt[l * DD + i] = acc;
}

__global__ void precompute_Weff(const float* __restrict__ Wcv,
                                const float* __restrict__ Wout,
                                float* __restrict__ Weff) {
    const int bh = blockIdx.x;
    const int h = bh >> 8, i = bh & 255;
    const int o = threadIdx.x;
    const float* wrow = Wcv + (size_t)i * DD;
    float acc = 0.f;
#pragma unroll 4
    for (int j = 0; j < DD; ++j)
        acc += wrow[j] * Wout[(size_t)(h * DD + j) * 128 + o];
    Weff[(size_t)bh * 128 + o] = acc;
}

// Swizzle all weights into MFMA B-fragment order, bf16, zero-padded K.
__global__ void layout_all(const float* __restrict__ Wown, const float* __restrict__ Wenv,
                           const float* __restrict__ Wsur, const float* __restrict__ Mt2f,
                           const float* __restrict__ Wvf,  const float* __restrict__ Wefff,
                           ushort* __restrict__ pre) {
    const int idx8 = blockIdx.x * blockDim.x + threadIdx.x;
    if (idx8 >= 49152) return;
    const float* src; int Ksrc, N, NT, local;
    if (idx8 < 3072)       { src=Wown;  Ksrc=80;  N=256; NT=16; local=idx8;        }
    else if (idx8 < 8192)  { src=Wenv;  Ksrc=160; N=256; NT=16; local=idx8-3072;   }
    else if (idx8 < 20480) { src=Wsur;  Ksrc=384; N=256; NT=16; local=idx8-8192;   }
    else if (idx8 < 28672) { src=Mt2f;  Ksrc=256; N=256; NT=16; local=idx8-20480;  }
    else if (idx8 < 36864) { src=Wvf;   Ksrc=256; N=256; NT=16; local=idx8-28672;  }
    else                   { src=Wefff; Ksrc=768; N=128; NT=8;  local=idx8-36864;  }
    const int lane = local & 63;
    const int nt   = (local >> 6) & (NT - 1);
    const int kc   = local / (64 * NT);
    const int n    = nt * 16 + (lane & 15);
    const int k0   = kc * 32 + (lane >> 4) * 8;
    union { ushort u[8]; uint4 q; } pk;
#pragma unroll
    for (int j = 0; j < 8; ++j) {
        const int k = k0 + j;
        pk.u[j] = (k < Ksrc) ? f2bf(src[(size_t)k * N + n]) : (ushort)0;
    }
    *(uint4*)(pre + (size_t)idx8 * 8) = pk.q;
}

// ---------------- main fused kernel ----------------
template<int NCH, int NTT, int NTW>
__device__ inline void gemm16(const char* sA, int strideA, const ushort* wpre,
                              char* swb, f32x4* acc, int w, int lane) {
    const int lm = lane & 15, lq = lane >> 4;
#pragma unroll
    for (int n = 0; n < NTW; ++n) acc[n] = (f32x4){0.f, 0.f, 0.f, 0.f};
    const int chunkB = NTT * 1024;
    const int perwave = chunkB / 4;
    for (int kc = 0; kc < NCH; ++kc) {
        __syncthreads();
        const char* src = (const char*)wpre + (size_t)kc * chunkB;
        for (int i = 0; i < perwave; i += 1024)
            gl2lds16(src + w * perwave + i + lane * 16, swb + w * perwave + i);
        __syncthreads();
        const bf16x8 af = *(const bf16x8*)(sA + lm * strideA + kc * 64 + lq * 16);
#pragma unroll
        for (int n = 0; n < NTW; ++n) {
            const bf16x8 bfr = *(const bf16x8*)(swb + ((size_t)(w * NTW + n) * 64 + lane) * 16);
            acc[n] = __builtin_amdgcn_mfma_f32_16x16x32_bf16(af, bfr, acc[n], 0, 0, 0);
        }
    }
}

__global__ __launch_bounds__(256, 2) void critic_mfma(
    const float* __restrict__ state0, const float* __restrict__ state1,
    const float* __restrict__ state2,
    const float* __restrict__ b_own, const float* __restrict__ b_env,
    const float* __restrict__ b_sur, const float* __restrict__ b_out,
    const float* __restrict__ W_j1, const float* __restrict__ b_j1,
    const float* __restrict__ W_j2, const float* __restrict__ b_j2,
    const ushort* __restrict__ pre_own, const ushort* __restrict__ pre_env,
    const ushort* __restrict__ pre_sur, const ushort* __restrict__ pre_mt2,
    const ushort* __restrict__ pre_wv,  const ushort* __restrict__ pre_weff,
    float* __restrict__ out) {

    __shared__ __align__(16) ushort s_cc[MB * 776];
    __shared__ __align__(16) ushort s_att[MB * 264];
    __shared__ __align__(16) char   s_w[16384];
    __shared__ __align__(16) char   s_a[10240];
    __shared__ float s_spart[2 * 128];   // [wn][row] — round 3 fix
    __shared__ float s_alpha[128];
    __shared__ float s_mask[128];

    const int t = threadIdx.x;
    const int lane = t & 63;
    const int w = t >> 6;
    const int lm = lane & 15, lq = lane >> 4;
    const int bbase = blockIdx.x * MB;

    {
        uint4 z; z.x = z.y = z.z = z.w = 0u;
        for (int i = t; i < 640; i += 256) ((uint4*)s_a)[i] = z;
    }
    __syncthreads();

    // ---- stage state0 -> s_a (16 rows x 80 f32 -> bf16, stride 240 B) ----
    if (t < 160) {
        const int row = t / 10, s = t % 10;
        const float* gp = state0 + (size_t)(bbase + row) * OBS0V + s * 8;
        pack_store8(s_a + row * 240 + s * 16, *(const float4*)gp, *(const float4*)(gp + 4));
    }
    __syncthreads();

    // ---- own = relu(state0 @ W_own + b_own) -> s_cc[:,0:256] ----
    {
        f32x4 acc[4];
        gemm16<3, 16, 4>((const char*)s_a, 240, pre_own, s_w, acc, w, lane);
#pragma unroll
        for (int n = 0; n < 4; ++n) {
            const int gc = (w * 4 + n) * 16 + lm;
            const float bv = b_own[gc];
#pragma unroll
            for (int r = 0; r < 4; ++r)
                s_cc[(size_t)(lq * 4 + r) * 776 + gc] = f2bf(fmaxf(acc[n][r] + bv, 0.f));
        }
    }
    __syncthreads();

    // ---- stage state1 -> s_a (16 x 160, stride 336 B) ----
    {
        const int row = t / 20, s = t % 20;
        const float* gp = state1 + (size_t)(bbase + row) * OBS1V + s * 8;
        pack_store8(s_a + row * 336 + s * 16, *(const float4*)gp, *(const float4*)(gp + 4));
        if (t < 64) {
            const int slot = t + 256, row2 = slot / 20, s2 = slot % 20;
            const float* gp2 = state1 + (size_t)(bbase + row2) * OBS1V + s2 * 8;
            pack_store8(s_a + row2 * 336 + s2 * 16, *(const float4*)gp2, *(const float4*)(gp2 + 4));
        }
    }
    __syncthreads();

    // ---- env = relu(state1 @ W_env + b_env) -> s_cc[:,256:512] ----
    {
        f32x4 acc[4];
        gemm16<5, 16, 4>((const char*)s_a, 336, pre_env, s_w, acc, w, lane);
#pragma unroll
        for (int n = 0; n < 4; ++n) {
            const int gc = (w * 4 + n) * 16 + lm;
            const float bv = b_env[gc];
#pragma unroll
            for (int r = 0; r < 4; ++r)
                s_cc[(size_t)(lq * 4 + r) * 776 + 256 + gc] = f2bf(fmaxf(acc[n][r] + bv, 0.f));
        }
    }
    __syncthreads();

    // ---- u = own @ Mt2 -> s_cc[:,512:768] (bf16, dead after score) ----
    {
        f32x4 acc[4];
        gemm16<8, 16, 4>((const char*)s_cc, 1552, pre_mt2, s_w, acc, w, lane);
#pragma unroll
        for (int n = 0; n < 4; ++n) {
            const int gc = (w * 4 + n) * 16 + lm;
#pragma unroll
            for (int r = 0; r < 4; ++r)
                s_cc[(size_t)(lq * 4 + r) * 776 + 512 + gc] = f2bf(acc[n][r]);
        }
    }

    // ---- sur GEMM: 128 (b,k)-rows x 384 -> 256, acc kept in C-fragments ----
    f32x4 sacc[4][8];
#pragma unroll
    for (int a = 0; a < 4; ++a)
#pragma unroll
        for (int b2 = 0; b2 < 8; ++b2) sacc[a][b2] = (f32x4){0.f, 0.f, 0.f, 0.f};
    float ms0 = 0.f, ms1 = 0.f;
    const int wm = w & 1, wn = w >> 1;
    const float* s2b = state2 + (size_t)bbase * KN * OBS2V;
    const int row0 = t >> 2, q0 = t & 3;

    for (int kc = 0; kc < 12; ++kc) {
        __syncthreads();
        const char* wsrc = (const char*)pre_sur + (size_t)kc * 16384;
        for (int i = 0; i < 4096; i += 1024)
            gl2lds16(wsrc + w * 4096 + i + lane * 16, s_w + w * 4096 + i);
        {
            const float* gp = s2b + (size_t)row0 * OBS2V + kc * 32 + q0 * 8;
            const float4 a0 = *(const float4*)gp;
            const float4 a1 = *(const float4*)(gp + 4);
            ms0 += a0.x + a0.y + a0.z + a0.w + a1.x + a1.y + a1.z + a1.w;
            pack_store8(s_a + row0 * 80 + q0 * 16, a0, a1);
            const float* gp1 = gp + (size_t)64 * OBS2V;
            const float4 c0 = *(const float4*)gp1;
            const float4 c1 = *(const float4*)(gp1 + 4);
            ms1 += c0.x + c0.y + c0.z + c0.w + c1.x + c1.y + c1.z + c1.w;
            pack_store8(s_a + (64 + row0) * 80 + q0 * 16, c0, c1);
        }
        __syncthreads();
        bf16x8 bfr[8];
#pragma unroll
        for (int n = 0; n < 8; ++n)
            bfr[n] = *(const bf16x8*)(s_w + ((size_t)(wn * 8 + n) * 64 + lane) * 16);
#pragma unroll
        for (int mt = 0; mt < 4; ++mt) {
            const int rowa = (wm * 4 + mt) * 16 + lm;
            const bf16x8 af = *(const bf16x8*)(s_a + rowa * 80 + lq * 16);
#pragma unroll
            for (int n = 0; n < 8; ++n)
                sacc[mt][n] = __builtin_amdgcn_mfma_f32_16x16x32_bf16(af, bfr[n], sacc[mt][n], 0, 0, 0);
        }
    }
    // mask sums -> s_mask
    {
        float p = ms0;
        p += __shfl_xor(p, 1); p += __shfl_xor(p, 2);
        if (q0 == 0) s_mask[row0] = p;
        float p2 = ms1;
        p2 += __shfl_xor(p2, 1); p2 += __shfl_xor(p2, 2);
        if (q0 == 0) s_mask[64 + row0] = p2;
    }
    // bias + relu on sur fragments
    {
        float bs[8];
#pragma unroll
        for (int n = 0; n < 8; ++n) bs[n] = b_sur[wn * 128 + n * 16 + lm];
#pragma unroll
        for (int mt = 0; mt < 4; ++mt)
#pragma unroll
            for (int n = 0; n < 8; ++n)
#pragma unroll
                for (int r = 0; r < 4; ++r)
                    sacc[mt][n][r] = fmaxf(sacc[mt][n][r] + bs[n], 0.f);
    }
    // score partials: each row gets one partial per column-half (wn)
#pragma unroll
    for (int mt = 0; mt < 4; ++mt) {
        const int tm = wm * 4 + mt;
        const int bb = 2 * tm + (lq >> 1);
        float u8[8];
#pragma unroll
        for (int n = 0; n < 8; ++n)
            u8[n] = bf2f(s_cc[(size_t)bb * 776 + 512 + wn * 128 + n * 16 + lm]);
#pragma unroll
        for (int r = 0; r < 4; ++r) {
            float p = 0.f;
#pragma unroll
            for (int n = 0; n < 8; ++n) p += sacc[mt][n][r] * u8[n];
            p += __shfl_xor(p, 1); p += __shfl_xor(p, 2);
            p += __shfl_xor(p, 4); p += __shfl_xor(p, 8);
            if (lm == 0) s_spart[wn * 128 + tm * 16 + lq * 4 + r] = p;   // FIX: wn not w
        }
    }
    __syncthreads();
    // softmax over k (16 threads, one per batch row)
    if (t < MB) {
        float sc[8]; float mx = -INFINITY;
#pragma unroll
        for (int k = 0; k < 8; ++k) {
            const int row = t * 8 + k;
            const float s = s_spart[row] + s_spart[128 + row];           // FIX: 2 halves
            sc[k] = (s_mask[row] != 0.f) ? s * 0.0625f : -INFINITY;
            mx = fmaxf(mx, sc[k]);
        }
        float e[8]; float dn = 0.f;
#pragma unroll
        for (int k = 0; k < 8; ++k) {
            e[k] = (sc[k] == -INFINITY) ? 0.f : __expf(sc[k] - mx);
            dn += e[k];
        }
        const float inv = (dn > 0.f) ? 1.f / dn : 0.f;
#pragma unroll
        for (int k = 0; k < 8; ++k) s_alpha[t * 8 + k] = e[k] * inv;
    }
    __syncthreads();
    // s_att[b] = sum_k alpha*sur -> s_att LDS (bf16)
#pragma unroll
    for (int mt = 0; mt < 4; ++mt) {
        const int tm = wm * 4 + mt;
        float al[4];
#pragma unroll
        for (int r = 0; r < 4; ++r) al[r] = s_alpha[tm * 16 + lq * 4 + r];
#pragma unroll
        for (int n = 0; n < 8; ++n) {
            float p = sacc[mt][n][0] * al[0] + sacc[mt][n][1] * al[1]
                    + sacc[mt][n][2] * al[2] + sacc[mt][n][3] * al[3];
            p += __shfl_xor(p, 16);
            const int col = wn * 128 + n * 16 + lm;
            if (lq == 0)      s_att[(size_t)(2 * tm) * 264 + col] = f2bf(p);
            else if (lq == 2) s_att[(size_t)(2 * tm + 1) * 264 + col] = f2bf(p);
        }
    }
    __syncthreads();

    // ---- v_att = s_att @ Wv -> s_cc[:,512:768] (overwrites dead u) ----
    {
        f32x4 acc[4];
        gemm16<8, 16, 4>((const char*)s_att, 528, pre_wv, s_w, acc, w, lane);
#pragma unroll
        for (int n = 0; n < 4; ++n) {
            const int gc = (w * 4 + n) * 16 + lm;
#pragma unroll
            for (int r = 0; r < 4; ++r)
                s_cc[(size_t)(lq * 4 + r) * 776 + 512 + gc] = f2bf(acc[n][r]);
        }
    }
    __syncthreads();

    // ---- multi = cc @ Weff + b_out -> s_multi (f32, aliases s_a) ----
    float* s_multi = (float*)s_a;
    {
        f32x4 acc[2];
        gemm16<24, 8, 2>((const char*)s_cc, 1552, pre_weff, s_w, acc, w, lane);
#pragma unroll
        for (int n = 0; n < 2; ++n) {
            const int gc = (w * 2 + n) * 16 + lm;
            const float bv = b_out[gc];
#pragma unroll
            for (int r = 0; r < 4; ++r)
                s_multi[(lq * 4 + r) * 128 + gc] = acc[n][r] + bv;
        }
    }
    __syncthreads();

    // ---- judgement tail (fp32) ----
    float hid[4];
#pragma unroll
    for (int p = 0; p < 4; ++p) {
        const int idx = t + 256 * p;
        const int b2 = idx >> 6, h = idx & 63;
        float a2 = b_j1[h];
#pragma unroll 4
        for (int o = 0; o < 128; ++o) a2 += s_multi[b2 * 128 + o] * W_j1[o * 64 + h];
        hid[p] = fmaxf(a2, 0.f);
    }
    float* s_hid = (float*)s_att;
    __syncthreads();
#pragma unroll
    for (int p = 0; p < 4; ++p) {
        const int idx = t + 256 * p;
        s_hid[(idx >> 6) * 64 + (idx & 63)] = hid[p];
    }
    __syncthreads();
    if (t < MB) {
        float a2 = b_j2[0];
#pragma unroll 4
        for (int h = 0; h < 64; ++h) a2 += s_hid[t * 64 + h] * W_j2[h];
        out[bbase + t] = a2;
    }
}

extern "C" void kernel_launch(void* const* d_in, const int* in_sizes, int n_in,
                              void* d_out, int out_size, void* d_ws, size_t ws_size,
                              hipStream_t stream) {
    (void)n_in; (void)out_size; (void)ws_size;
    const float* state0 = (const float*)d_in[0];
    const float* state1 = (const float*)d_in[1];
    const float* state2 = (const float*)d_in[2];
    const float* W_own  = (const float*)d_in[3];
    const float* b_own  = (const float*)d_in[4];
    const float* W_env  = (const float*)d_in[5];
    const float* b_env  = (const float*)d_in[6];
    const float* W_sur  = (const float*)d_in[7];
    const float* b_sur  = (const float*)d_in[8];
    const float* Wq     = (const float*)d_in[9];
    const float* Wk     = (const float*)d_in[10];
    const float* Wv     = (const float*)d_in[11];
    // d_in[12]=Wcq, d_in[13]=Wck: dead (seq_len==1 softmax == 1)
    const float* Wcv    = (const float*)d_in[14];
    const float* W_out  = (const float*)d_in[15];
    const float* b_out  = (const float*)d_in[16];
    const float* W_j1   = (const float*)d_in[17];
    const float* b_j1   = (const float*)d_in[18];
    const float* W_j2   = (const float*)d_in[19];
    const float* b_j2   = (const float*)d_in[20];
    float* out = (float*)d_out;

    float* Mt2f  = (float*)d_ws;
    float* Wefff = Mt2f + 65536;
    ushort* pre  = (ushort*)((char*)d_ws + 655360);
    ushort* pre_own  = pre;
    ushort* pre_env  = pre + 24576;
    ushort* pre_sur  = pre + 65536;
    ushort* pre_mt2  = pre + 163840;
    ushort* pre_wv   = pre + 229376;
    ushort* pre_weff = pre + 294912;

    const int B = in_sizes[0] / OBS0V;

    precompute_M<<<256, 256, 0, stream>>>(Wk, Wq, Mt2f);
    precompute_Weff<<<768, 128, 0, stream>>>(Wcv, W_out, Wefff);
    layout_all<<<192, 256, 0, stream>>>(W_own, W_env, W_sur, Mt2f, Wv, Wefff, pre);
    critic_mfma<<<B / MB, 256, 0, stream>>>(state0, state1, state2,
        b_own, b_env, b_sur, b_out, W_j1, b_j1, W_j2, b_j2,
        pre_own, pre_env, pre_sur, pre_mt2, pre_wv, pre_weff, out);
}